// Round 5
// baseline (142.533 us; speedup 1.0000x reference)
//
#include <hip/hip_runtime.h>
#include <hip/hip_bf16.h>
#include <stdint.h>

// Shapes fixed by the reference: N=8192, F_IN=128, F_OUT=64.
// THIS ROUND = byte-identical round-2 (last PASS) with exactly one logical
// change: j-split S 8 -> 2 (dim3(128,2), jb=by*4096, 16 stages). Everything
// else (k_init/flag, atomics, scalar k3, ws offsets) untouched for
// differential debugging of the round-3/4 NaNs.
typedef float f32x4 __attribute__((ext_vector_type(4)));
typedef short s16x8 __attribute__((ext_vector_type(8)));
typedef unsigned int u32x4 __attribute__((ext_vector_type(4)));

#define L2E 1.44269504088896f  // log2(e)

__device__ __forceinline__ float bf2f(unsigned short u) {
    return __uint_as_float(((unsigned int)u) << 16);
}
__device__ __forceinline__ unsigned short f2bf_rne(float f) {
    unsigned int u = __float_as_uint(f);
    u += 0x7fffu + ((u >> 16) & 1u);
    return (unsigned short)(u >> 16);
}

// ---------------------------------------------------------------------------
// k_init: zero the atomic accumulators (ws is poisoned 0xAA before each call)
// and, in block 0, detect the input dtype (kept identical to round 2).
// Grid: 520 x 256.
// ---------------------------------------------------------------------------
__global__ __launch_bounds__(256) void k_init(
    const unsigned short* __restrict__ Wu,
    int* __restrict__ flag,
    float* __restrict__ Apart,
    float* __restrict__ rsum)
{
    int gid = blockIdx.x * 256 + threadIdx.x;
    f32x4 z = (f32x4){0.f, 0.f, 0.f, 0.f};
    if (gid < 131072)       *(f32x4*)&Apart[gid * 4] = z;
    else if (gid < 133120)  *(f32x4*)&rsum[(gid - 131072) * 4] = z;

    if (blockIdx.x == 0) {
        __shared__ int any;
        if (threadIdx.x == 0) any = 0;
        __syncthreads();
        int loc = 0;
        for (int i = threadIdx.x; i < 8192; i += 256) {
            unsigned e = (Wu[i] >> 7) & 0xFFu;  // bf16-exponent field
            loc |= (e >= 0xC0u);                // not plausible bf16 data
        }
        if (loc) atomicOr(&any, 1);
        __syncthreads();
        if (threadIdx.x == 0) flag[0] = any;    // 1 => inputs are f32
    }
}

// ---------------------------------------------------------------------------
// k1: Wh = h@W (MFMA, bf16 internally), f1L=(Wh@a1)*log2e, f2L=(Wh@a2)*log2e,
//     whT[n][i] = bf16(Wh[i][n]). Identical to round 2.
// Grid: 128 x 256; block = 64 rows.
// ---------------------------------------------------------------------------
__global__ __launch_bounds__(256) void k1_wh(
    const void* __restrict__ hv,
    const void* __restrict__ Wv,
    const void* __restrict__ av,
    const int* __restrict__ flag,
    unsigned short* __restrict__ whT,
    float* __restrict__ f1L,
    float* __restrict__ f2L)
{
    __shared__ __align__(16) unsigned short tb[64][72];  // [n][i_local], 144B rows
    const int isF32 = flag[0];
    const unsigned short* hu = (const unsigned short*)hv;
    const float*          hf = (const float*)hv;
    const unsigned short* Wu = (const unsigned short*)Wv;
    const float*          Wf = (const float*)Wv;
    const unsigned short* au = (const unsigned short*)av;
    const float*          af = (const float*)av;

    const int tid  = threadIdx.x;
    const int lane = tid & 63;
    const int w    = tid >> 6;
    const int col  = lane & 15;
    const int quad = lane >> 4;
    const int i0   = blockIdx.x * 64;

    f32x4 D[4];
    #pragma unroll
    for (int f = 0; f < 4; ++f) D[f] = (f32x4){0.f, 0.f, 0.f, 0.f};

    const int rowA = i0 + w * 16 + col;  // A operand: m = lane&15
    #pragma unroll
    for (int cs = 0; cs < 4; ++cs) {     // K = 128 in 4 steps of 32
        s16x8 A;
        if (isF32) {
            f32x4 h0 = *(const f32x4*)&hf[(size_t)rowA * 128 + cs * 32 + quad * 8];
            f32x4 h1 = *(const f32x4*)&hf[(size_t)rowA * 128 + cs * 32 + quad * 8 + 4];
            #pragma unroll
            for (int jj = 0; jj < 4; ++jj) {
                A[jj]     = (short)f2bf_rne(h0[jj]);
                A[4 + jj] = (short)f2bf_rne(h1[jj]);
            }
        } else {
            A = *(const s16x8*)&hu[(size_t)rowA * 128 + cs * 32 + quad * 8];
        }
        #pragma unroll
        for (int f = 0; f < 4; ++f) {    // n0 = f*16; B[k][n]: n=lane&15, k=quad*8+jj
            s16x8 B;
            #pragma unroll
            for (int jj = 0; jj < 8; ++jj) {
                int widx = (cs * 32 + quad * 8 + jj) * 64 + f * 16 + col;
                B[jj] = isF32 ? (short)f2bf_rne(Wf[widx]) : (short)Wu[widx];
            }
            D[f] = __builtin_amdgcn_mfma_f32_16x16x32_bf16(A, B, D[f], 0, 0, 0);
        }
    }

    float a1v[4], a2v[4];
    #pragma unroll
    for (int f = 0; f < 4; ++f) {
        a1v[f] = isF32 ? af[f * 16 + col]      : bf2f(au[f * 16 + col]);
        a2v[f] = isF32 ? af[64 + f * 16 + col] : bf2f(au[64 + f * 16 + col]);
    }

    // D layout: row = quad*4 + r, col-of-Wh = f*16 + (lane&15)
    #pragma unroll
    for (int r = 0; r < 4; ++r) {
        float s1 = D[0][r]*a1v[0] + D[1][r]*a1v[1] + D[2][r]*a1v[2] + D[3][r]*a1v[3];
        float s2 = D[0][r]*a2v[0] + D[1][r]*a2v[1] + D[2][r]*a2v[2] + D[3][r]*a2v[3];
        #pragma unroll
        for (int d = 1; d < 16; d <<= 1) {  // reduce over the 16 cols
            s1 += __shfl_xor(s1, d, 64);
            s2 += __shfl_xor(s2, d, 64);
        }
        if (col == 0) {
            int i = i0 + w * 16 + quad * 4 + r;
            f1L[i] = s1 * L2E;
            f2L[i] = s2 * L2E;
        }
        #pragma unroll
        for (int f = 0; f < 4; ++f)
            tb[f * 16 + col][w * 16 + quad * 4 + r] = f2bf_rne(D[f][r]);
    }
    __syncthreads();
    for (int idx = tid; idx < 512; idx += 256) {  // coalesced transposed write
        int n = idx >> 3, c8 = (idx & 7) << 3;
        *(u32x4*)&whT[(size_t)n * 8192 + i0 + c8] = *(const u32x4*)&tb[n][c8];
    }
}

// ---------------------------------------------------------------------------
// k2: fused attention: for 64 rows x one 4096-j chunk, accumulate
//     Apart[i][n] += sum_j p_ij * Wh[j][n]  and  rsum[i] += sum_j p_ij
// Identical to round 2 except: jb = by*4096, 16 stages (S: 8 -> 2).
// Grid: (128 row-tiles, 2 j-chunks) x 256 thr.
// ---------------------------------------------------------------------------
__global__ __launch_bounds__(256) void k2_attn(
    const unsigned short* __restrict__ whT,
    const float* __restrict__ f1L,
    const float* __restrict__ f2L,
    float* __restrict__ Apart,
    float* __restrict__ rsum)
{
    __shared__ __align__(16) unsigned short Bt[64][264];  // [n][j_local], 256 + 8 pad
    __shared__ __align__(16) float f2s[256];              // per-stage f2 slice
    const int tid  = threadIdx.x;
    const int lane = tid & 63;
    const int w    = tid >> 6;
    const int col  = lane & 15;
    const int quad = lane >> 4;
    const int i0   = blockIdx.x * 64;
    const int jb   = blockIdx.y * 4096;

    const float f1 = f1L[i0 + w * 16 + col];  // A-fragment row m = lane&15

    f32x4 D0 = (f32x4){0.f,0.f,0.f,0.f}, D1 = D0, D2 = D0, D3 = D0, Ds = D0;
    s16x8 ones;
    #pragma unroll
    for (int jj = 0; jj < 8; ++jj) ones[jj] = (short)0x3f80;  // bf16(1.0)

    for (int s = 0; s < 16; ++s) {           // 16 stages x 256 j
        __syncthreads();
        if (tid < 64)
            *(f32x4*)&f2s[tid * 4] = *(const f32x4*)&f2L[jb + (s << 8) + tid * 4];
        for (int idx = tid; idx < 2048; idx += 256) {  // stage 64 x 256 bf16 tile
            int n = idx >> 5, c = (idx & 31) << 3;
            *(u32x4*)&Bt[n][c] =
                *(const u32x4*)&whT[(size_t)n * 8192 + jb + (s << 8) + c];
        }
        __syncthreads();
        #pragma unroll
        for (int j0 = 0; j0 < 256; j0 += 32) {
            const int jq = j0 + quad * 8;
            f32x4 fa = *(const f32x4*)&f2s[jq];
            f32x4 fb = *(const f32x4*)&f2s[jq + 4];
            unsigned int pb[8];
            #pragma unroll
            for (int e = 0; e < 4; ++e) {
                float u = f1 + fa[e];                       // already *log2e
                u = fmaxf(u, 0.01f * u);                    // LeakyReLU in log2 domain
                u = fminf(fmaxf(u, -126.f), 80.f);          // NaN/Inf insurance
                pb[e] = __float_as_uint(__builtin_amdgcn_exp2f(u));
                float v = f1 + fb[e];
                v = fmaxf(v, 0.01f * v);
                v = fminf(fmaxf(v, -126.f), 80.f);
                pb[4 + e] = __float_as_uint(__builtin_amdgcn_exp2f(v));
            }
            union { u32x4 u4; s16x8 s8; } Au;   // pack truncated bf16 pairs
            Au.u4[0] = __builtin_amdgcn_perm(pb[1], pb[0], 0x07060302u);
            Au.u4[1] = __builtin_amdgcn_perm(pb[3], pb[2], 0x07060302u);
            Au.u4[2] = __builtin_amdgcn_perm(pb[5], pb[4], 0x07060302u);
            Au.u4[3] = __builtin_amdgcn_perm(pb[7], pb[6], 0x07060302u);
            const int jc = j0 + quad * 8;
            s16x8 B0 = *(const s16x8*)&Bt[col][jc];
            s16x8 B1 = *(const s16x8*)&Bt[16 + col][jc];
            s16x8 B2 = *(const s16x8*)&Bt[32 + col][jc];
            s16x8 B3 = *(const s16x8*)&Bt[48 + col][jc];
            D0 = __builtin_amdgcn_mfma_f32_16x16x32_bf16(Au.s8, B0, D0, 0, 0, 0);
            D1 = __builtin_amdgcn_mfma_f32_16x16x32_bf16(Au.s8, B1, D1, 0, 0, 0);
            D2 = __builtin_amdgcn_mfma_f32_16x16x32_bf16(Au.s8, B2, D2, 0, 0, 0);
            D3 = __builtin_amdgcn_mfma_f32_16x16x32_bf16(Au.s8, B3, D3, 0, 0, 0);
            Ds = __builtin_amdgcn_mfma_f32_16x16x32_bf16(Au.s8, ones, Ds, 0, 0, 0);
        }
    }

    #pragma unroll
    for (int r = 0; r < 4; ++r) {   // D layout: row = quad*4+r, col n = 16*b + col
        int i = i0 + w * 16 + quad * 4 + r;
        atomicAdd(&Apart[(size_t)i * 64 +      col], D0[r]);
        atomicAdd(&Apart[(size_t)i * 64 + 16 + col], D1[r]);
        atomicAdd(&Apart[(size_t)i * 64 + 32 + col], D2[r]);
        atomicAdd(&Apart[(size_t)i * 64 + 48 + col], D3[r]);
        if (col == 0) atomicAdd(&rsum[i], Ds[r]);
    }
}

// ---------------------------------------------------------------------------
// k3: out = elu(Apart / rsum), written as bf16 or f32 per detected dtype.
// Identical to round 2.
// ---------------------------------------------------------------------------
__global__ __launch_bounds__(256) void k3_combine(
    const float* __restrict__ Apart,
    const float* __restrict__ rsum,
    const int* __restrict__ flag,
    void* __restrict__ outv)
{
    int gid = blockIdx.x * 256 + threadIdx.x;  // 0 .. 524287
    int i = gid >> 6;
    float v = Apart[gid] / rsum[i];
    float r = v > 0.f ? v : (__builtin_amdgcn_exp2f(v * L2E) - 1.f);
    if (flag[0]) ((float*)outv)[gid] = r;
    else         ((unsigned short*)outv)[gid] = f2bf_rne(r);
}

// ---------------------------------------------------------------------------
extern "C" void kernel_launch(void* const* d_in, const int* in_sizes, int n_in,
                              void* d_out, int out_size, void* d_ws, size_t ws_size,
                              hipStream_t stream) {
    const void* h = d_in[0];  // 8192x128
    const void* W = d_in[1];  // 128x64
    const void* a = d_in[2];  // 128x1

    char* ws = (char*)d_ws;
    unsigned short* whT = (unsigned short*)ws;        // 64x8192 bf16 = 1 MB
    float* f1L   = (float*)(ws + 1048576);            // 32 KB
    float* f2L   = (float*)(ws + 1081344);            // 32 KB
    int*   flag  = (int*)  (ws + 1114112);            // 16 B
    float* Apart = (float*)(ws + 1114368);            // 8192x64 f32 = 2 MB
    float* rsum  = (float*)(ws + 3211520);            // 8192 f32 = 32 KB
    // total ws requirement: ~3.25 MB (ws_size ~256 MB per round-2 fill counters)

    k_init<<<520, 256, 0, stream>>>((const unsigned short*)W, flag, Apart, rsum);
    k1_wh<<<128, 256, 0, stream>>>(h, W, a, flag, whT, f1L, f2L);
    k2_attn<<<dim3(128, 2), 256, 0, stream>>>(whT, f1L, f2L, Apart, rsum);
    k3_combine<<<2048, 256, 0, stream>>>(Apart, rsum, flag, d_out);
}

// Round 6
// 123.409 us; speedup vs baseline: 1.1550x; 1.1550x over previous
//
#include <hip/hip_runtime.h>
#include <hip/hip_bf16.h>
#include <stdint.h>

// Shapes fixed by the reference: N=8192, F_IN=128, F_OUT=64.
// Proven skeleton = round 2/5 (k_init+flag, MFMA k1, atomicAdd k2, k3).
// Round-6 single change: 4 contention slots for Apart/rsum (blockIdx.y & 3)
// to cut atomic same-address serialization 4x. Everything else byte-identical
// to round 2 (last fast PASS). Plain-store partial designs (rounds 1/3/4)
// NaN'd for unknown reasons -- do not revisit without new evidence.
typedef float f32x4 __attribute__((ext_vector_type(4)));
typedef short s16x8 __attribute__((ext_vector_type(8)));
typedef unsigned int u32x4 __attribute__((ext_vector_type(4)));

#define L2E 1.44269504088896f  // log2(e)

__device__ __forceinline__ float bf2f(unsigned short u) {
    return __uint_as_float(((unsigned int)u) << 16);
}
__device__ __forceinline__ unsigned short f2bf_rne(float f) {
    unsigned int u = __float_as_uint(f);
    u += 0x7fffu + ((u >> 16) & 1u);
    return (unsigned short)(u >> 16);
}

// ---------------------------------------------------------------------------
// k_init: zero the 4-slot atomic accumulators (ws poisoned 0xAA each call)
// and, in block 0, detect input dtype (kept from round 2).
// Grid: 2080 x 256 (532480 f32x4 stores = 4*(524288+8192) floats).
// ---------------------------------------------------------------------------
__global__ __launch_bounds__(256) void k_init(
    const unsigned short* __restrict__ Wu,
    int* __restrict__ flag,
    float* __restrict__ Apart,
    float* __restrict__ rsum)
{
    int gid = blockIdx.x * 256 + threadIdx.x;
    f32x4 z = (f32x4){0.f, 0.f, 0.f, 0.f};
    if (gid < 524288)       *(f32x4*)&Apart[(size_t)gid * 4] = z;
    else if (gid < 532480)  *(f32x4*)&rsum[(size_t)(gid - 524288) * 4] = z;

    if (blockIdx.x == 0) {
        __shared__ int any;
        if (threadIdx.x == 0) any = 0;
        __syncthreads();
        int loc = 0;
        for (int i = threadIdx.x; i < 8192; i += 256) {
            unsigned e = (Wu[i] >> 7) & 0xFFu;  // bf16-exponent field
            loc |= (e >= 0xC0u);                // not plausible bf16 data
        }
        if (loc) atomicOr(&any, 1);
        __syncthreads();
        if (threadIdx.x == 0) flag[0] = any;    // 1 => inputs are f32
    }
}

// ---------------------------------------------------------------------------
// k1: Wh = h@W (MFMA, bf16 internally), f1L=(Wh@a1)*log2e, f2L=(Wh@a2)*log2e,
//     whT[n][i] = bf16(Wh[i][n]). Identical to round 2.
// Grid: 128 x 256; block = 64 rows.
// ---------------------------------------------------------------------------
__global__ __launch_bounds__(256) void k1_wh(
    const void* __restrict__ hv,
    const void* __restrict__ Wv,
    const void* __restrict__ av,
    const int* __restrict__ flag,
    unsigned short* __restrict__ whT,
    float* __restrict__ f1L,
    float* __restrict__ f2L)
{
    __shared__ __align__(16) unsigned short tb[64][72];  // [n][i_local], 144B rows
    const int isF32 = flag[0];
    const unsigned short* hu = (const unsigned short*)hv;
    const float*          hf = (const float*)hv;
    const unsigned short* Wu = (const unsigned short*)Wv;
    const float*          Wf = (const float*)Wv;
    const unsigned short* au = (const unsigned short*)av;
    const float*          af = (const float*)av;

    const int tid  = threadIdx.x;
    const int lane = tid & 63;
    const int w    = tid >> 6;
    const int col  = lane & 15;
    const int quad = lane >> 4;
    const int i0   = blockIdx.x * 64;

    f32x4 D[4];
    #pragma unroll
    for (int f = 0; f < 4; ++f) D[f] = (f32x4){0.f, 0.f, 0.f, 0.f};

    const int rowA = i0 + w * 16 + col;  // A operand: m = lane&15
    #pragma unroll
    for (int cs = 0; cs < 4; ++cs) {     // K = 128 in 4 steps of 32
        s16x8 A;
        if (isF32) {
            f32x4 h0 = *(const f32x4*)&hf[(size_t)rowA * 128 + cs * 32 + quad * 8];
            f32x4 h1 = *(const f32x4*)&hf[(size_t)rowA * 128 + cs * 32 + quad * 8 + 4];
            #pragma unroll
            for (int jj = 0; jj < 4; ++jj) {
                A[jj]     = (short)f2bf_rne(h0[jj]);
                A[4 + jj] = (short)f2bf_rne(h1[jj]);
            }
        } else {
            A = *(const s16x8*)&hu[(size_t)rowA * 128 + cs * 32 + quad * 8];
        }
        #pragma unroll
        for (int f = 0; f < 4; ++f) {    // n0 = f*16; B[k][n]: n=lane&15, k=quad*8+jj
            s16x8 B;
            #pragma unroll
            for (int jj = 0; jj < 8; ++jj) {
                int widx = (cs * 32 + quad * 8 + jj) * 64 + f * 16 + col;
                B[jj] = isF32 ? (short)f2bf_rne(Wf[widx]) : (short)Wu[widx];
            }
            D[f] = __builtin_amdgcn_mfma_f32_16x16x32_bf16(A, B, D[f], 0, 0, 0);
        }
    }

    float a1v[4], a2v[4];
    #pragma unroll
    for (int f = 0; f < 4; ++f) {
        a1v[f] = isF32 ? af[f * 16 + col]      : bf2f(au[f * 16 + col]);
        a2v[f] = isF32 ? af[64 + f * 16 + col] : bf2f(au[64 + f * 16 + col]);
    }

    // D layout: row = quad*4 + r, col-of-Wh = f*16 + (lane&15)
    #pragma unroll
    for (int r = 0; r < 4; ++r) {
        float s1 = D[0][r]*a1v[0] + D[1][r]*a1v[1] + D[2][r]*a1v[2] + D[3][r]*a1v[3];
        float s2 = D[0][r]*a2v[0] + D[1][r]*a2v[1] + D[2][r]*a2v[2] + D[3][r]*a2v[3];
        #pragma unroll
        for (int d = 1; d < 16; d <<= 1) {  // reduce over the 16 cols
            s1 += __shfl_xor(s1, d, 64);
            s2 += __shfl_xor(s2, d, 64);
        }
        if (col == 0) {
            int i = i0 + w * 16 + quad * 4 + r;
            f1L[i] = s1 * L2E;
            f2L[i] = s2 * L2E;
        }
        #pragma unroll
        for (int f = 0; f < 4; ++f)
            tb[f * 16 + col][w * 16 + quad * 4 + r] = f2bf_rne(D[f][r]);
    }
    __syncthreads();
    for (int idx = tid; idx < 512; idx += 256) {  // coalesced transposed write
        int n = idx >> 3, c8 = (idx & 7) << 3;
        *(u32x4*)&whT[(size_t)n * 8192 + i0 + c8] = *(const u32x4*)&tb[n][c8];
    }
}

// ---------------------------------------------------------------------------
// k2: fused attention: for 64 rows x one 1024-j chunk, accumulate into slot
// (blockIdx.y & 3):  Apart[slot][i][n] += sum_j p_ij * Wh[j][n],
//                    rsum[slot][i]     += sum_j p_ij
// Identical to round 2 except the slot selection on the atomic targets.
// Grid: (128 row-tiles, 8 j-chunks) x 256 thr.
// ---------------------------------------------------------------------------
__global__ __launch_bounds__(256) void k2_attn(
    const unsigned short* __restrict__ whT,
    const float* __restrict__ f1L,
    const float* __restrict__ f2L,
    float* __restrict__ Apart,
    float* __restrict__ rsum)
{
    __shared__ __align__(16) unsigned short Bt[64][264];  // [n][j_local], 256 + 8 pad
    __shared__ __align__(16) float f2s[256];              // per-stage f2 slice
    const int tid  = threadIdx.x;
    const int lane = tid & 63;
    const int w    = tid >> 6;
    const int col  = lane & 15;
    const int quad = lane >> 4;
    const int i0   = blockIdx.x * 64;
    const int jb   = blockIdx.y * 1024;

    const float f1 = f1L[i0 + w * 16 + col];  // A-fragment row m = lane&15

    f32x4 D0 = (f32x4){0.f,0.f,0.f,0.f}, D1 = D0, D2 = D0, D3 = D0, Ds = D0;
    s16x8 ones;
    #pragma unroll
    for (int jj = 0; jj < 8; ++jj) ones[jj] = (short)0x3f80;  // bf16(1.0)

    for (int s = 0; s < 4; ++s) {            // 4 stages x 256 j
        __syncthreads();
        if (tid < 64)
            *(f32x4*)&f2s[tid * 4] = *(const f32x4*)&f2L[jb + (s << 8) + tid * 4];
        for (int idx = tid; idx < 2048; idx += 256) {  // stage 64 x 256 bf16 tile
            int n = idx >> 5, c = (idx & 31) << 3;
            *(u32x4*)&Bt[n][c] =
                *(const u32x4*)&whT[(size_t)n * 8192 + jb + (s << 8) + c];
        }
        __syncthreads();
        #pragma unroll
        for (int j0 = 0; j0 < 256; j0 += 32) {
            const int jq = j0 + quad * 8;
            f32x4 fa = *(const f32x4*)&f2s[jq];
            f32x4 fb = *(const f32x4*)&f2s[jq + 4];
            unsigned int pb[8];
            #pragma unroll
            for (int e = 0; e < 4; ++e) {
                float u = f1 + fa[e];                       // already *log2e
                u = fmaxf(u, 0.01f * u);                    // LeakyReLU in log2 domain
                u = fminf(fmaxf(u, -126.f), 80.f);          // NaN/Inf insurance
                pb[e] = __float_as_uint(__builtin_amdgcn_exp2f(u));
                float v = f1 + fb[e];
                v = fmaxf(v, 0.01f * v);
                v = fminf(fmaxf(v, -126.f), 80.f);
                pb[4 + e] = __float_as_uint(__builtin_amdgcn_exp2f(v));
            }
            union { u32x4 u4; s16x8 s8; } Au;   // pack truncated bf16 pairs
            Au.u4[0] = __builtin_amdgcn_perm(pb[1], pb[0], 0x07060302u);
            Au.u4[1] = __builtin_amdgcn_perm(pb[3], pb[2], 0x07060302u);
            Au.u4[2] = __builtin_amdgcn_perm(pb[5], pb[4], 0x07060302u);
            Au.u4[3] = __builtin_amdgcn_perm(pb[7], pb[6], 0x07060302u);
            const int jc = j0 + quad * 8;
            s16x8 B0 = *(const s16x8*)&Bt[col][jc];
            s16x8 B1 = *(const s16x8*)&Bt[16 + col][jc];
            s16x8 B2 = *(const s16x8*)&Bt[32 + col][jc];
            s16x8 B3 = *(const s16x8*)&Bt[48 + col][jc];
            D0 = __builtin_amdgcn_mfma_f32_16x16x32_bf16(Au.s8, B0, D0, 0, 0, 0);
            D1 = __builtin_amdgcn_mfma_f32_16x16x32_bf16(Au.s8, B1, D1, 0, 0, 0);
            D2 = __builtin_amdgcn_mfma_f32_16x16x32_bf16(Au.s8, B2, D2, 0, 0, 0);
            D3 = __builtin_amdgcn_mfma_f32_16x16x32_bf16(Au.s8, B3, D3, 0, 0, 0);
            Ds = __builtin_amdgcn_mfma_f32_16x16x32_bf16(Au.s8, ones, Ds, 0, 0, 0);
        }
    }

    const int slot = blockIdx.y & 3;            // contention /4
    float* Ap = Apart + (size_t)slot * 524288;
    float* rs = rsum  + (size_t)slot * 8192;
    #pragma unroll
    for (int r = 0; r < 4; ++r) {   // D layout: row = quad*4+r, col n = 16*b + col
        int i = i0 + w * 16 + quad * 4 + r;
        atomicAdd(&Ap[(size_t)i * 64 +      col], D0[r]);
        atomicAdd(&Ap[(size_t)i * 64 + 16 + col], D1[r]);
        atomicAdd(&Ap[(size_t)i * 64 + 32 + col], D2[r]);
        atomicAdd(&Ap[(size_t)i * 64 + 48 + col], D3[r]);
        if (col == 0) atomicAdd(&rs[i], Ds[r]);
    }
}

// ---------------------------------------------------------------------------
// k3: out = elu( (sum_s Apart[s]) / (sum_s rsum[s]) ), bf16 or f32 per flag.
// Round-2 structure, extended to sum the 4 slots.
// ---------------------------------------------------------------------------
__global__ __launch_bounds__(256) void k3_combine(
    const float* __restrict__ Apart,
    const float* __restrict__ rsum,
    const int* __restrict__ flag,
    void* __restrict__ outv)
{
    int gid = blockIdx.x * 256 + threadIdx.x;  // 0 .. 524287
    int i = gid >> 6;
    float num = 0.f, den = 0.f;
    #pragma unroll
    for (int s = 0; s < 4; ++s) {
        num += Apart[(size_t)s * 524288 + gid];
        den += rsum[s * 8192 + i];
    }
    float v = num / den;
    float r = v > 0.f ? v : (__builtin_amdgcn_exp2f(v * L2E) - 1.f);
    if (flag[0]) ((float*)outv)[gid] = r;
    else         ((unsigned short*)outv)[gid] = f2bf_rne(r);
}

// ---------------------------------------------------------------------------
extern "C" void kernel_launch(void* const* d_in, const int* in_sizes, int n_in,
                              void* d_out, int out_size, void* d_ws, size_t ws_size,
                              hipStream_t stream) {
    const void* h = d_in[0];  // 8192x128
    const void* W = d_in[1];  // 128x64
    const void* a = d_in[2];  // 128x1

    char* ws = (char*)d_ws;
    unsigned short* whT = (unsigned short*)ws;        // 64x8192 bf16 = 1 MB
    float* f1L   = (float*)(ws + 1048576);            // 32 KB
    float* f2L   = (float*)(ws + 1081344);            // 32 KB
    int*   flag  = (int*)  (ws + 1114112);            // 16 B
    float* Apart = (float*)(ws + 1114368);            // 4 x 8192x64 f32 = 8 MB
    float* rsum  = (float*)(ws + 9502976);            // 4 x 8192 f32 = 128 KB
    // total ws requirement: ~9.6 MB (ws_size ~256 MB per fill counters)

    k_init<<<2080, 256, 0, stream>>>((const unsigned short*)W, flag, Apart, rsum);
    k1_wh<<<128, 256, 0, stream>>>(h, W, a, flag, whT, f1L, f2L);
    k2_attn<<<dim3(128, 8), 256, 0, stream>>>(whT, f1L, f2L, Apart, rsum);
    k3_combine<<<2048, 256, 0, stream>>>(Apart, rsum, flag, d_out);
}

// Round 7
// 94.585 us; speedup vs baseline: 1.5069x; 1.3047x over previous
//
#include <hip/hip_runtime.h>
#include <hip/hip_bf16.h>
#include <stdint.h>

// Shapes fixed by the reference: N=8192, F_IN=128, F_OUT=64.
// DTYPE RESOLUTION (round 6): inputs AND output are f32. Evidence: round 2
// passed while its k3 wrote f32 through the flag[0]!=0 branch; every round
// that hard-coded bf16 input reads (1,3,4) NaN'd; every detector round
// (2,5,6) passed. Internal compute stays bf16 MFMA (absmax 3.9e-3 << 1.49e-2).
// This round: hard-code f32, delete detector/k_init/atomics; k2 plain-stores
// per-chunk partials (8 slots), k3 combines.
typedef float f32x4 __attribute__((ext_vector_type(4)));
typedef short s16x8 __attribute__((ext_vector_type(8)));
typedef unsigned int u32x4 __attribute__((ext_vector_type(4)));

#define L2E 1.44269504088896f  // log2(e)

__device__ __forceinline__ unsigned short f2bf_rne(float f) {
    unsigned int u = __float_as_uint(f);
    u += 0x7fffu + ((u >> 16) & 1u);
    return (unsigned short)(u >> 16);
}

// ---------------------------------------------------------------------------
// k1: Wh = h@W (bf16 MFMA), f1L=(Wh@a1)*log2e, f2L=(Wh@a2)*log2e,
//     whT[n][i] = bf16(Wh[i][n])  (transposed for k2's B-fragment loads).
// f32 inputs, converted to bf16 in-register. Grid: 128 x 256; block = 64 rows.
// ---------------------------------------------------------------------------
__global__ __launch_bounds__(256) void k1_wh(
    const float* __restrict__ hf,
    const float* __restrict__ Wf,
    const float* __restrict__ af,
    unsigned short* __restrict__ whT,
    float* __restrict__ f1L,
    float* __restrict__ f2L)
{
    __shared__ __align__(16) unsigned short tb[64][72];  // [n][i_local], 144B rows
    const int tid  = threadIdx.x;
    const int lane = tid & 63;
    const int w    = tid >> 6;
    const int col  = lane & 15;
    const int quad = lane >> 4;
    const int i0   = blockIdx.x * 64;

    f32x4 D[4];
    #pragma unroll
    for (int f = 0; f < 4; ++f) D[f] = (f32x4){0.f, 0.f, 0.f, 0.f};

    const int rowA = i0 + w * 16 + col;  // A operand: m = lane&15
    #pragma unroll
    for (int cs = 0; cs < 4; ++cs) {     // K = 128 in 4 steps of 32
        f32x4 h0 = *(const f32x4*)&hf[(size_t)rowA * 128 + cs * 32 + quad * 8];
        f32x4 h1 = *(const f32x4*)&hf[(size_t)rowA * 128 + cs * 32 + quad * 8 + 4];
        s16x8 A;
        #pragma unroll
        for (int jj = 0; jj < 4; ++jj) {
            A[jj]     = (short)f2bf_rne(h0[jj]);
            A[4 + jj] = (short)f2bf_rne(h1[jj]);
        }
        #pragma unroll
        for (int f = 0; f < 4; ++f) {    // n0 = f*16; B[k][n]: n=lane&15, k=quad*8+jj
            s16x8 B;
            #pragma unroll
            for (int jj = 0; jj < 8; ++jj)
                B[jj] = (short)f2bf_rne(Wf[(cs * 32 + quad * 8 + jj) * 64 + f * 16 + col]);
            D[f] = __builtin_amdgcn_mfma_f32_16x16x32_bf16(A, B, D[f], 0, 0, 0);
        }
    }

    float a1v[4], a2v[4];
    #pragma unroll
    for (int f = 0; f < 4; ++f) {
        a1v[f] = af[f * 16 + col];
        a2v[f] = af[64 + f * 16 + col];
    }

    // D layout: row = quad*4 + r, col-of-Wh = f*16 + (lane&15)
    #pragma unroll
    for (int r = 0; r < 4; ++r) {
        float s1 = D[0][r]*a1v[0] + D[1][r]*a1v[1] + D[2][r]*a1v[2] + D[3][r]*a1v[3];
        float s2 = D[0][r]*a2v[0] + D[1][r]*a2v[1] + D[2][r]*a2v[2] + D[3][r]*a2v[3];
        #pragma unroll
        for (int d = 1; d < 16; d <<= 1) {  // reduce over the 16 cols
            s1 += __shfl_xor(s1, d, 64);
            s2 += __shfl_xor(s2, d, 64);
        }
        if (col == 0) {
            int i = i0 + w * 16 + quad * 4 + r;
            f1L[i] = s1 * L2E;
            f2L[i] = s2 * L2E;
        }
        #pragma unroll
        for (int f = 0; f < 4; ++f)
            tb[f * 16 + col][w * 16 + quad * 4 + r] = f2bf_rne(D[f][r]);
    }
    __syncthreads();
    for (int idx = tid; idx < 512; idx += 256) {  // coalesced transposed write
        int n = idx >> 3, c8 = (idx & 7) << 3;
        *(u32x4*)&whT[(size_t)n * 8192 + i0 + c8] = *(const u32x4*)&tb[n][c8];
    }
}

// ---------------------------------------------------------------------------
// k2: fused attention partials: for 64 rows x one 1024-j chunk,
//     Apart[s][i][n] = sum_j p_ij * Wh[j][n],  rsumP[s][i] = sum_j p_ij
// p built in registers directly in MFMA A-fragment layout; denominator via a
// 5th MFMA against an all-ones B fragment (same bf16 p -> ratio errors cancel).
// Plain stores to per-chunk slots, no atomics. Grid: (128, 8) x 256.
// ---------------------------------------------------------------------------
__global__ __launch_bounds__(256) void k2_attn(
    const unsigned short* __restrict__ whT,
    const float* __restrict__ f1L,
    const float* __restrict__ f2L,
    float* __restrict__ Apart,
    float* __restrict__ rsumP)
{
    __shared__ __align__(16) unsigned short Bt[64][264];  // [n][j_local], 256 + 8 pad
    __shared__ __align__(16) float f2s[256];              // per-stage f2 slice
    const int tid  = threadIdx.x;
    const int lane = tid & 63;
    const int w    = tid >> 6;
    const int col  = lane & 15;
    const int quad = lane >> 4;
    const int i0   = blockIdx.x * 64;
    const int jb   = blockIdx.y * 1024;

    const float f1 = f1L[i0 + w * 16 + col];  // A-fragment row m = lane&15

    f32x4 D0 = (f32x4){0.f,0.f,0.f,0.f}, D1 = D0, D2 = D0, D3 = D0, Ds = D0;
    s16x8 ones;
    #pragma unroll
    for (int jj = 0; jj < 8; ++jj) ones[jj] = (short)0x3f80;  // bf16(1.0)

    for (int s = 0; s < 4; ++s) {            // 4 stages x 256 j
        __syncthreads();
        if (tid < 64)
            *(f32x4*)&f2s[tid * 4] = *(const f32x4*)&f2L[jb + (s << 8) + tid * 4];
        for (int idx = tid; idx < 2048; idx += 256) {  // stage 64 x 256 bf16 tile
            int n = idx >> 5, c = (idx & 31) << 3;
            *(u32x4*)&Bt[n][c] =
                *(const u32x4*)&whT[(size_t)n * 8192 + jb + (s << 8) + c];
        }
        __syncthreads();
        #pragma unroll
        for (int j0 = 0; j0 < 256; j0 += 32) {
            const int jq = j0 + quad * 8;
            f32x4 fa = *(const f32x4*)&f2s[jq];
            f32x4 fb = *(const f32x4*)&f2s[jq + 4];
            unsigned int pb[8];
            #pragma unroll
            for (int e = 0; e < 4; ++e) {
                float u = f1 + fa[e];                       // already *log2e
                u = fmaxf(u, 0.01f * u);                    // LeakyReLU in log2 domain
                u = fminf(fmaxf(u, -126.f), 80.f);          // NaN/Inf insurance
                pb[e] = __float_as_uint(__builtin_amdgcn_exp2f(u));
                float v = f1 + fb[e];
                v = fmaxf(v, 0.01f * v);
                v = fminf(fmaxf(v, -126.f), 80.f);
                pb[4 + e] = __float_as_uint(__builtin_amdgcn_exp2f(v));
            }
            union { u32x4 u4; s16x8 s8; } Au;   // pack truncated bf16 pairs
            Au.u4[0] = __builtin_amdgcn_perm(pb[1], pb[0], 0x07060302u);
            Au.u4[1] = __builtin_amdgcn_perm(pb[3], pb[2], 0x07060302u);
            Au.u4[2] = __builtin_amdgcn_perm(pb[5], pb[4], 0x07060302u);
            Au.u4[3] = __builtin_amdgcn_perm(pb[7], pb[6], 0x07060302u);
            s16x8 B0 = *(const s16x8*)&Bt[col][jq];
            s16x8 B1 = *(const s16x8*)&Bt[16 + col][jq];
            s16x8 B2 = *(const s16x8*)&Bt[32 + col][jq];
            s16x8 B3 = *(const s16x8*)&Bt[48 + col][jq];
            D0 = __builtin_amdgcn_mfma_f32_16x16x32_bf16(Au.s8, B0, D0, 0, 0, 0);
            D1 = __builtin_amdgcn_mfma_f32_16x16x32_bf16(Au.s8, B1, D1, 0, 0, 0);
            D2 = __builtin_amdgcn_mfma_f32_16x16x32_bf16(Au.s8, B2, D2, 0, 0, 0);
            D3 = __builtin_amdgcn_mfma_f32_16x16x32_bf16(Au.s8, B3, D3, 0, 0, 0);
            Ds = __builtin_amdgcn_mfma_f32_16x16x32_bf16(Au.s8, ones, Ds, 0, 0, 0);
        }
    }

    float* Ap = Apart + (size_t)blockIdx.y * 524288;
    #pragma unroll
    for (int r = 0; r < 4; ++r) {   // D layout: row = quad*4+r, col n = 16*b + col
        int i = i0 + w * 16 + quad * 4 + r;
        Ap[(size_t)i * 64 +      col] = D0[r];
        Ap[(size_t)i * 64 + 16 + col] = D1[r];
        Ap[(size_t)i * 64 + 32 + col] = D2[r];
        Ap[(size_t)i * 64 + 48 + col] = D3[r];
        if (col == 0) rsumP[blockIdx.y * 8192 + i] = Ds[r];
    }
}

// ---------------------------------------------------------------------------
// k3: out(f32) = elu( sum_s Apart[s] / sum_s rsumP[s] ), vectorized x4.
// Grid: 512 x 256 (131072 threads, 4 cols each).
// ---------------------------------------------------------------------------
__global__ __launch_bounds__(256) void k3_combine(
    const float* __restrict__ Apart,
    const float* __restrict__ rsumP,
    float* __restrict__ out)
{
    int gid = blockIdx.x * 256 + threadIdx.x;  // 0 .. 131071
    int i  = gid >> 4;
    int c4 = (gid & 15) << 2;
    f32x4 num = (f32x4){0.f, 0.f, 0.f, 0.f};
    float den = 0.f;
    #pragma unroll
    for (int s = 0; s < 8; ++s) {
        num += *(const f32x4*)&Apart[(size_t)s * 524288 + (size_t)i * 64 + c4];
        den += rsumP[s * 8192 + i];
    }
    float rden = 1.f / den;
    f32x4 o;
    #pragma unroll
    for (int e = 0; e < 4; ++e) {
        float v = num[e] * rden;
        o[e] = v > 0.f ? v : (__builtin_amdgcn_exp2f(v * L2E) - 1.f);
    }
    *(f32x4*)&out[(size_t)i * 64 + c4] = o;
}

// ---------------------------------------------------------------------------
extern "C" void kernel_launch(void* const* d_in, const int* in_sizes, int n_in,
                              void* d_out, int out_size, void* d_ws, size_t ws_size,
                              hipStream_t stream) {
    const float* h = (const float*)d_in[0];  // 8192x128 f32
    const float* W = (const float*)d_in[1];  // 128x64 f32
    const float* a = (const float*)d_in[2];  // 128x1 f32
    float* out = (float*)d_out;              // 8192x64 f32

    char* ws = (char*)d_ws;
    unsigned short* whT = (unsigned short*)ws;        // 64x8192 bf16 = 1 MB
    float* f1L   = (float*)(ws + 1048576);            // 32 KB
    float* f2L   = (float*)(ws + 1081344);            // 32 KB
    float* Apart = (float*)(ws + 1114112);            // 8 x 8192x64 f32 = 16 MB
    float* rsumP = (float*)(ws + 17891328);           // 8 x 8192 f32 = 256 KB
    // total ws ~18.1 MB (ws_size ~256 MB per fill counters)

    k1_wh<<<128, 256, 0, stream>>>(h, W, a, whT, f1L, f2L);
    k2_attn<<<dim3(128, 8), 256, 0, stream>>>(whT, f1L, f2L, Apart, rsumP);
    k3_combine<<<512, 256, 0, stream>>>(Apart, rsumP, out);
}